// Round 13
// baseline (413.911 us; speedup 1.0000x reference)
//
#include <hip/hip_runtime.h>
#include <hip/hip_bf16.h>

// Geometry (fixed): B=1, C=8, D=H=W=128.
constexpr int HW2 = 16384;
constexpr int DHW = 2097152;

// MFMA staging: LDS cell = 8 ci (bf16, 16 B) at (slot = dz*4+ry, xi).
constexpr int PKG = 13;
constexpr int XT  = 130;  // staged x extent: x = -1 .. 128

typedef short bf16x8 __attribute__((ext_vector_type(8)));  // 8 bf16 = 4 VGPR
typedef float f32x4  __attribute__((ext_vector_type(4)));

__device__ inline unsigned short f2b(float f) {
  __hip_bfloat16 h = __float2bfloat16(f);
  return *(unsigned short*)&h;
}
__device__ inline float b2f(unsigned short u) {
  __hip_bfloat16 h = *(__hip_bfloat16*)&u;
  return __bfloat162float(h);
}

// ---------------------------------------------------------------------------
// Prep: pack w1/w2 into MFMA A-fragment order, bf16, dx-split.
// Slot g = s*4+q interpreted as (dz = g>>2 = s, dy = g&3 = q); dy==3 -> 0.
// Tail zero-fills 32-B guards around ti/xi (adapt x-halo reads).
// ---------------------------------------------------------------------------
__global__ __launch_bounds__(256) void k_prep(
    const float* __restrict__ w1, const float* __restrict__ w2,
    unsigned short* __restrict__ Wpack2, unsigned short* __restrict__ Wpack1,
    float* __restrict__ g_ti, float* __restrict__ g_xi) {
  int i = blockIdx.x * 256 + threadIdx.x;
  if (i < 9216) {
    int j = i & 7;
    int lane = (i >> 3) & 63;
    int Mt = (i >> 9) & 1;
    int g2 = i >> 10;         // dx*3 + s
    int s = g2 % 3, dx = g2 / 3;
    int oc = Mt * 16 + (lane & 15);
    int kr = s * 32 + (lane >> 4) * 8 + j;
    int ci = kr & 7, g = kr >> 3;          // g = s*4 + q
    float w = 0.f;
    if (oc < 27 && (g & 3) < 3) {
      int dzr = g >> 2, dyr = g & 3;
      w = w2[(oc * 8 + ci) * 27 + dzr * 9 + dyr * 3 + dx];
    }
    Wpack2[i] = f2b(w);
  }
  int jj = i - 9216;
  if (jj >= 0 && jj < 4608) {
    int j = jj & 7;
    int lane = (jj >> 3) & 63;
    int g2 = jj >> 9;         // dx*3 + s
    int s = g2 % 3, dx = g2 / 3;
    int oc = lane & 15;
    int kr = s * 32 + (lane >> 4) * 8 + j;
    int ci = kr & 7, g = kr >> 3;
    float w = 0.f;
    if (oc < 8 && (g & 3) < 3) {
      int dzr = g >> 2, dyr = g & 3;
      w = w1[(oc * 8 + ci) * 27 + dzr * 9 + dyr * 3 + dx];
    }
    Wpack1[jj] = f2b(w);
  }
  int gg = i - 13824;
  if (gg >= 0 && gg < 32) {
    float* p = (gg < 8)  ? (g_ti - 8 + gg)
             : (gg < 16) ? (g_ti + (size_t)8 * DHW + (gg - 8))
             : (gg < 24) ? (g_xi - 8 + (gg - 16))
                         : (g_xi + (size_t)8 * DHW + (gg - 24));
    *p = 0.f;
  }
}

// ---------------------------------------------------------------------------
// Transpose x: [ci][z][y][x] fp32 -> [z][y][x][ci] bf16 (xb, for conv1 MFMA)
//                                 and [z][y][x][ci] fp32 (xi, for adapt pass)
// ---------------------------------------------------------------------------
__global__ __launch_bounds__(256) void k_xpose(
    const float* __restrict__ x, unsigned short* __restrict__ xb,
    float* __restrict__ xi) {
  int idx = blockIdx.x * 256 + threadIdx.x;  // voxel
  float f[8];
  unsigned v[4];
#pragma unroll
  for (int p = 0; p < 4; ++p) {
    f[2 * p]     = x[(size_t)(2 * p) * DHW + idx];
    f[2 * p + 1] = x[(size_t)(2 * p + 1) * DHW + idx];
    unsigned lo = f2b(f[2 * p]);
    unsigned hi = f2b(f[2 * p + 1]);
    v[p] = lo | (hi << 16);
  }
  ((uint4*)xb)[idx] = make_uint4(v[0], v[1], v[2], v[3]);
  float4* xo = (float4*)(xi + (size_t)idx * 8);
  xo[0] = make_float4(f[0], f[1], f[2], f[3]);
  xo[1] = make_float4(f[4], f[5], f[6], f[7]);
}

// ---------------------------------------------------------------------------
// Shared conv staging (R7 y-pair, proven): batched-MLP, division-free.
// ---------------------------------------------------------------------------
#define STAGE_ROWS2(srcp)                                                  \
  {                                                                        \
    if (tid < 154) {                                                       \
      if (tid < 130) {                                                     \
        dst[tid * PKG + 12] = make_uint4(0u, 0u, 0u, 0u);                  \
      } else {                                                             \
        int k = tid - 130;                                                 \
        int sl = k >> 1, xih = (k & 1) ? 129 : 0;                          \
        dst[xih * PKG + sl] = make_uint4(0u, 0u, 0u, 0u);                  \
      }                                                                    \
    }                                                                      \
    const int gg = tid >> 7;                                               \
    const int xi_ = (tid & 127) + 1;                                       \
    const int xg_ = xi_ - 1;                                               \
    uint4 sv[6];                                                           \
    bool vld[6];                                                           \
    _Pragma("unroll")                                                      \
    for (int it = 0; it < 6; ++it) {                                       \
      const int g = gg + it * 2;                                           \
      const int dz = g >> 2, ry = g & 3;                                   \
      const int z = z0 + dz - 1, y = y0 + ry - 1;                          \
      vld[it] = ((unsigned)z < 128u) & ((unsigned)y < 128u);               \
      const int zz = vld[it] ? z : z0, yy = vld[it] ? y : y0;              \
      sv[it] = (srcp)[(zz * 128 + yy) * 128 + xg_];                        \
    }                                                                      \
    _Pragma("unroll")                                                      \
    for (int it = 0; it < 6; ++it) {                                       \
      const int g = gg + it * 2;                                           \
      uint4 v = vld[it] ? sv[it] : make_uint4(0u, 0u, 0u, 0u);             \
      dst[xi_ * PKG + g] = v;                                              \
    }                                                                      \
  }

// ---------------------------------------------------------------------------
// Kernel 1: conv3d(x, w1) + bias + ReLU (8 -> 8), implicit-GEMM MFMA.
// y-pair per block; grid 128 z * 64 ypairs = 8192.
// ---------------------------------------------------------------------------
__global__ __launch_bounds__(256, 3) void k_conv1m(
    const unsigned short* __restrict__ xb,
    const unsigned short* __restrict__ Wpack1,
    const float* __restrict__ b1, unsigned short* __restrict__ hb) {
  __shared__ __align__(16) unsigned short T[XT * PKG * 8];
  const int tid  = threadIdx.x;
  const int lane = tid & 63;
  const int wv   = tid >> 6;
  const int logical = (blockIdx.x & 7) * 1024 + (blockIdx.x >> 3);
  const int z0 = logical >> 6;
  const int y0 = (logical & 63) * 2;

  bf16x8 wf[3][3];
  {
    const bf16x8* wp = (const bf16x8*)Wpack1;
#pragma unroll
    for (int dx = 0; dx < 3; ++dx)
#pragma unroll
      for (int s = 0; s < 3; ++s)
        wf[dx][s] = wp[(dx * 3 + s) * 64 + lane];
  }

  const uint4* src = (const uint4*)xb;
  uint4* dst = (uint4*)T;
  STAGE_ROWS2(src);
  __syncthreads();

  f32x4 acc[2][2];  // [r][nt]
#pragma unroll
  for (int r = 0; r < 2; ++r)
#pragma unroll
    for (int nt = 0; nt < 2; ++nt) acc[r][nt] = (f32x4){0.f, 0.f, 0.f, 0.f};

  const int n = lane & 15;
  const int q = lane >> 4;
  const int xbase = wv * 32 + n;

#pragma unroll
  for (int dx = 0; dx < 3; ++dx) {
#pragma unroll
    for (int s = 0; s < 3; ++s) {
      bf16x8 bfr[2][2];
#pragma unroll
      for (int r = 0; r < 2; ++r)
#pragma unroll
        for (int nt = 0; nt < 2; ++nt) {
          int off = ((xbase + nt * 16 + dx) * PKG + (s * 4 + q + r)) * 8;
          bfr[r][nt] = *(const bf16x8*)&T[off];
        }
#pragma unroll
      for (int r = 0; r < 2; ++r)
#pragma unroll
        for (int nt = 0; nt < 2; ++nt)
          acc[r][nt] = __builtin_amdgcn_mfma_f32_16x16x32_bf16(
              wf[dx][s], bfr[r][nt], acc[r][nt], 0, 0, 0);
    }
  }

  if (q < 2) {
#pragma unroll
    for (int r = 0; r < 2; ++r) {
      const int voxrow = (z0 * 128 + y0 + r) * 128;
#pragma unroll
      for (int nt = 0; nt < 2; ++nt) {
        const int vox = voxrow + wv * 32 + nt * 16 + n;
        ushort4 o;
        o.x = f2b(fmaxf(acc[r][nt][0] + b1[q * 4 + 0], 0.f));
        o.y = f2b(fmaxf(acc[r][nt][1] + b1[q * 4 + 1], 0.f));
        o.z = f2b(fmaxf(acc[r][nt][2] + b1[q * 4 + 2], 0.f));
        o.w = f2b(fmaxf(acc[r][nt][3] + b1[q * 4 + 3], 0.f));
        *(ushort4*)(hb + (size_t)vox * 8 + q * 4) = o;
      }
    }
  }
}

// ---------------------------------------------------------------------------
// Kernel 2: conv3d(h, w2) (8 -> 27) + fused L1 norm, implicit-GEMM MFMA.
// y-pair per block; grid 8192.
// ---------------------------------------------------------------------------
__global__ __launch_bounds__(256, 2) void k_conv2(
    const unsigned short* __restrict__ hb,
    const unsigned short* __restrict__ Wpack2,
    unsigned short* __restrict__ wn) {
  __shared__ __align__(16) unsigned short T[XT * PKG * 8];
  const int tid  = threadIdx.x;
  const int lane = tid & 63;
  const int wv   = tid >> 6;
  const int logical = (blockIdx.x & 7) * 1024 + (blockIdx.x >> 3);
  const int z0 = logical >> 6;
  const int y0 = (logical & 63) * 2;

  bf16x8 wf[3][3][2];
  {
    const bf16x8* wp = (const bf16x8*)Wpack2;
#pragma unroll
    for (int dx = 0; dx < 3; ++dx)
#pragma unroll
      for (int s = 0; s < 3; ++s)
#pragma unroll
        for (int mt = 0; mt < 2; ++mt)
          wf[dx][s][mt] = wp[((dx * 3 + s) * 2 + mt) * 64 + lane];
  }

  const uint4* src = (const uint4*)hb;
  uint4* dst = (uint4*)T;
  STAGE_ROWS2(src);
  __syncthreads();

  f32x4 acc[2][2][2];  // [r][nt][mt]
#pragma unroll
  for (int r = 0; r < 2; ++r)
#pragma unroll
    for (int nt = 0; nt < 2; ++nt)
#pragma unroll
      for (int mt = 0; mt < 2; ++mt)
        acc[r][nt][mt] = (f32x4){0.f, 0.f, 0.f, 0.f};

  const int n = lane & 15;
  const int q = lane >> 4;
  const int xbase = wv * 32 + n;

#pragma unroll
  for (int dx = 0; dx < 3; ++dx) {
#pragma unroll
    for (int s = 0; s < 3; ++s) {
      bf16x8 bfr[2][2];
#pragma unroll
      for (int r = 0; r < 2; ++r)
#pragma unroll
        for (int nt = 0; nt < 2; ++nt) {
          int off = ((xbase + nt * 16 + dx) * PKG + (s * 4 + q + r)) * 8;
          bfr[r][nt] = *(const bf16x8*)&T[off];
        }
#pragma unroll
      for (int r = 0; r < 2; ++r)
#pragma unroll
        for (int mt = 0; mt < 2; ++mt)
#pragma unroll
          for (int nt = 0; nt < 2; ++nt)
            acc[r][nt][mt] = __builtin_amdgcn_mfma_f32_16x16x32_bf16(
                wf[dx][s][mt], bfr[r][nt], acc[r][nt][mt], 0, 0, 0);
    }
  }

#pragma unroll
  for (int r = 0; r < 2; ++r) {
    const int voxrow = (z0 * 128 + y0 + r) * 128;
#pragma unroll
    for (int nt = 0; nt < 2; ++nt) {
      float ns = 0.f;
#pragma unroll
      for (int rr = 0; rr < 4; ++rr) ns += fabsf(acc[r][nt][0][rr]);
#pragma unroll
      for (int rr = 0; rr < 4; ++rr) {
        int oc = 16 + q * 4 + rr;
        ns += (oc < 27) ? fabsf(acc[r][nt][1][rr]) : 0.f;
      }
      ns += __shfl_xor(ns, 16);
      ns += __shfl_xor(ns, 32);
      float sc = 1.f / fmaxf(ns, 1e-12f);
      const int vox = voxrow + wv * 32 + nt * 16 + n;
#pragma unroll
      for (int rr = 0; rr < 4; ++rr) {
        int oc = q * 4 + rr;
        wn[(size_t)oc * DHW + vox] = f2b(acc[r][nt][0][rr] * sc);
      }
#pragma unroll
      for (int rr = 0; rr < 4; ++rr) {
        int oc = 16 + q * 4 + rr;
        if (oc < 27)
          wn[(size_t)oc * DHW + vox] = f2b(acc[r][nt][1][rr] * sc);
      }
    }
  }
}

// ---------------------------------------------------------------------------
// Kernel 3 (R13): quad-tiled adaptive conv + wn dz-ping-pong.
// R12 measured clean (no spill, FETCH 104/WRITE 64 MB) but only 60 us/pass:
// the wall is the per-dz wn global-load latency chain (18 in-loop loads per
// unroll-1 dz iteration, ~300 cy each, un-hoistable across the back-edge).
// Fix: depth-1 software pipeline with STATIC buffer names (rule #20):
//   load wnA(dz0) BEFORE the barrier (hides under staging drain);
//   load wnB(dz1); compute(wnA,0); load wnA(dz2); compute(wnB,1);
//   compute(wnA,2).
// Live-set delta vs R12: +18 VGPR only. launch_bounds(256,1) kept (R12
// proved honest allocation at this bound; R8's spill was under (256,2)).
// Staging / halo / swizzle / store bodies byte-identical to R12.
// ---------------------------------------------------------------------------
constexpr int APITCH = 2112;  // 66 slots * 32 B
__device__ inline int swz7(int off) { return off ^ (((off >> 7) & 7) << 4); }

#define AD_LOAD_WN(BUF, DZ)                                               \
  {                                                                       \
    _Pragma("unroll")                                                     \
    for (int t = 0; t < 9; ++t) {                                         \
      BUF[t] =                                                            \
          *(const unsigned*)(wn + (size_t)((DZ) * 9 + t) * DHW + voxp0);  \
      BUF[9 + t] = *(const unsigned*)(wn + (size_t)((DZ) * 9 + t) * DHW + \
                                      voxp0 + 128);                       \
    }                                                                     \
  }

#define AD_COMPUTE_DZ(BUF, DZ)                                            \
  {                                                                       \
    _Pragma("unroll")                                                     \
    for (int yr = 0; yr < 4; ++yr) {                                      \
      const char* R = S + ((zo + (DZ)) * 6 + 2 * yp + yr) * APITCH;       \
      f32x4 W[4][2];                                                      \
      _Pragma("unroll")                                                   \
      for (int j = 0; j < 4; ++j)                                         \
        _Pragma("unroll")                                                 \
        for (int h = 0; h < 2; ++h)                                       \
          W[j][h] = *(const f32x4*)(R + soff[j][h]);                      \
      _Pragma("unroll")                                                   \
      for (int oy = 0; oy < 2; ++oy) {                                    \
        const int dy = yr - oy;                                           \
        if (dy >= 0 && dy < 3) {                                          \
          const bool val = zok[(DZ)] && yok[oy][dy];                      \
          _Pragma("unroll")                                               \
          for (int dxi = 0; dxi < 3; ++dxi) {                             \
            const unsigned u = BUF[oy * 9 + dy * 3 + dxi];                \
            const float w0 =                                              \
                val ? b2f((unsigned short)(u & 0xffffu)) : 0.f;           \
            const float w1 = val ? b2f((unsigned short)(u >> 16)) : 0.f;  \
            _Pragma("unroll")                                             \
            for (int h = 0; h < 2; ++h)                                   \
              _Pragma("unroll")                                           \
              for (int c = 0; c < 4; ++c) {                               \
                acc[oy][0][h][c] =                                        \
                    fmaf(W[dxi][h][c], w0, acc[oy][0][h][c]);             \
                acc[oy][1][h][c] =                                        \
                    fmaf(W[dxi + 1][h][c], w1, acc[oy][1][h][c]);         \
              }                                                           \
          }                                                               \
        }                                                                 \
      }                                                                   \
    }                                                                     \
  }

template <int FINAL>
__global__ __launch_bounds__(256, 1) void k_adapt9(
    const float* __restrict__ in, const unsigned short* __restrict__ wn,
    float* __restrict__ out) {
  __shared__ __align__(16) char S[36 * APITCH];  // 76032 B
  const int tid = threadIdx.x;
  // grid 2048; XCD-chunked bijective swizzle, chunk 256.
  const int logical = (blockIdx.x & 7) * 256 + (blockIdx.x >> 3);
  const int xh  = logical & 1;
  const int typ = (logical >> 1) & 31;
  const int tzp = logical >> 6;
  const int x0 = xh * 64, y0 = typ * 4, z0 = tzp * 4;

  // compute-role indices (needed early for wn prefetch)
  const int xp = tid & 31;
  const int yp = (tid >> 5) & 1;
  const int zo = tid >> 6;
  const int Y = y0 + 2 * yp;
  const int Z = z0 + zo;
  const size_t voxp0 = (size_t)(Z * 128 + Y) * 128 + x0 + 2 * xp;

  // ---- staging: interior (x = x0..x0+63): 36 rows x 128 uint4.
  const int th = tid >> 7;        // 0/1
  const int kcol = tid & 127;
  const int wbyte = swz7(32 + kcol * 16);
#pragma unroll 1
  for (int ib = 0; ib < 2; ++ib) {  // two batches of 9 rounds (MLP 9)
    uint4 stg[9];
#pragma unroll
    for (int i = 0; i < 9; ++i) {
      const int r = 2 * (ib * 9 + i) + th;
      const int r6 = r / 6;
      const int zs = min(max(z0 - 1 + r6, 0), 127);
      const int ys = min(max(y0 - 1 + (r - r6 * 6), 0), 127);
      stg[i] = *(const uint4*)(in + (size_t)(zs * 128 + ys) * 1024 +
                               x0 * 8 + kcol * 4);
    }
#pragma unroll
    for (int i = 0; i < 9; ++i) {
      const int r = 2 * (ib * 9 + i) + th;
      *(uint4*)(S + r * APITCH + wbyte) = stg[i];
    }
  }
  // ---- halo columns: slot 0 (x0-1) and slot 65 (x0+64); 144 threads.
  if (tid < 144) {
    const int hr = tid >> 2;        // row 0..35
    const int hp = tid & 3;         // 0,1 -> slot 0 halves; 2,3 -> slot 65
    const int r6 = hr / 6;
    const int zs = min(max(z0 - 1 + r6, 0), 127);
    const int ys = min(max(y0 - 1 + (hr - r6 * 6), 0), 127);
    const int fo = (hp < 2) ? ((x0 - 1) * 8 + hp * 4)
                            : ((x0 + 64) * 8 + (hp - 2) * 4);
    uint4 v = *(const uint4*)(in + (size_t)(zs * 128 + ys) * 1024 + fo);
    const bool zero = xh ? (hp >= 2) : (hp < 2);  // global x=-1 / x=128
    if (zero) v = make_uint4(0u, 0u, 0u, 0u);
    const int sb = (hp < 2) ? (hp * 16) : (65 * 32 + (hp - 2) * 16);
    *(uint4*)(S + hr * APITCH + swz7(sb)) = v;
  }

  // ---- wn prefetch for dz=0 (latency hides under staging drain + barrier)
  unsigned wnA[18], wnB[18];
  AD_LOAD_WN(wnA, 0);
  __syncthreads();

  bool zok[3];
#pragma unroll
  for (int d = 0; d < 3; ++d) zok[d] = (unsigned)(Z + d - 1) < 128u;
  bool yok[2][3];
#pragma unroll
  for (int oy = 0; oy < 2; ++oy)
#pragma unroll
    for (int d = 0; d < 3; ++d)
      yok[oy][d] = (unsigned)(Y + oy + d - 1) < 128u;

  int soff[4][2];
#pragma unroll
  for (int j = 0; j < 4; ++j)
#pragma unroll
    for (int h = 0; h < 2; ++h)
      soff[j][h] = swz7((2 * xp + j) * 32 + h * 16);

  f32x4 acc[2][2][2];  // [oy][ox][h], all-static indexing
#pragma unroll
  for (int oy = 0; oy < 2; ++oy)
#pragma unroll
    for (int ox = 0; ox < 2; ++ox)
#pragma unroll
      for (int h = 0; h < 2; ++h)
        acc[oy][ox][h] = (f32x4){0.f, 0.f, 0.f, 0.f};

  // ---- dz pipeline: load next dz's wn while computing current ----
  AD_LOAD_WN(wnB, 1);
  AD_COMPUTE_DZ(wnA, 0);
  AD_LOAD_WN(wnA, 2);
  AD_COMPUTE_DZ(wnB, 1);
  AD_COMPUTE_DZ(wnA, 2);

  if (FINAL) {
    // planar fp32 [c][vox] -> d_out; float2 = x-pair
#pragma unroll
    for (int oy = 0; oy < 2; ++oy) {
      const size_t voxp = voxp0 + (size_t)oy * 128;
#pragma unroll
      for (int h = 0; h < 2; ++h)
#pragma unroll
        for (int c = 0; c < 4; ++c) {
          float2 o = make_float2(acc[oy][0][h][c], acc[oy][1][h][c]);
          *(float2*)(out + (size_t)(h * 4 + c) * DHW + voxp) = o;
        }
    }
  } else {
    // interleaved fp32 [vox][8]; 64 B contiguous per thread per y
#pragma unroll
    for (int oy = 0; oy < 2; ++oy) {
      const size_t voxp = voxp0 + (size_t)oy * 128;
      f32x4* op = (f32x4*)(out + voxp * 8);
      op[0] = acc[oy][0][0];
      op[1] = acc[oy][0][1];
      op[2] = acc[oy][1][0];
      op[3] = acc[oy][1][1];
    }
  }
}

// ---------------------------------------------------------------------------
extern "C" void kernel_launch(void* const* d_in, const int* in_sizes, int n_in,
                              void* d_out, int out_size, void* d_ws, size_t ws_size,
                              hipStream_t stream) {
  const float* x  = (const float*)d_in[0];
  const float* w1 = (const float*)d_in[1];
  const float* b1 = (const float*)d_in[2];
  const float* w2 = (const float*)d_in[3];
  float* out = (float*)d_out;

  // Workspace (~236 MiB + pads):
  //   [0,   64M): xb(32M)+hb(32M) bf16; reused as ti = ws+256 (64M fp32)
  //   [64M+4K, 172M+4K): wn bf16 planar (27 x DHW)
  //   [172M+12K, 236M+12K): xi fp32 interleaved
  //   then Wpack2, Wpack1. Guard zeros at ti/xi +-32 B (k_prep tail).
  char* ws = (char*)d_ws;
  unsigned short* xb = (unsigned short*)ws;
  unsigned short* hb = (unsigned short*)(ws + (size_t)8 * DHW * 2);
  float* ti = (float*)(ws + 256);  // aliases xb+hb (both dead before adapt)
  unsigned short* wn = (unsigned short*)(ws + (size_t)16 * DHW * 2 + 4096);
  float* xi = (float*)(ws + (size_t)16 * DHW * 2 + 4096 +
                       (size_t)27 * DHW * 2 + 8192);
  unsigned short* Wpack2 =
      (unsigned short*)((char*)xi + (size_t)8 * DHW * 4 + 16384);
  unsigned short* Wpack1 = Wpack2 + 9216;

  dim3 blk(256);
  k_prep<<<55, blk, 0, stream>>>(w1, w2, Wpack2, Wpack1, ti, xi);
  k_xpose<<<DHW / 256, blk, 0, stream>>>(x, xb, xi);
  k_conv1m<<<128 * 64, blk, 0, stream>>>(xb, Wpack1, b1, hb);
  k_conv2<<<128 * 64, blk, 0, stream>>>(hb, Wpack2, wn);
  // adaptive ping-pong on interleaved fp32: xi -> ti -> xi -> out (planar)
  k_adapt9<0><<<2048, blk, 0, stream>>>(xi, wn, ti);
  k_adapt9<0><<<2048, blk, 0, stream>>>(ti, wn, xi);
  k_adapt9<1><<<2048, blk, 0, stream>>>(xi, wn, out);
}

// Round 14
// 363.148 us; speedup vs baseline: 1.1398x; 1.1398x over previous
//
#include <hip/hip_runtime.h>
#include <hip/hip_bf16.h>

// Geometry (fixed): B=1, C=8, D=H=W=128.
constexpr int HW2 = 16384;
constexpr int DHW = 2097152;

// Conv MFMA staging (R14 y-quad): LDS cell = 8 ci (bf16, 16 B) at
// (slot = dz*8 + ry, xi). ry 0..5 = staged y rows (y0-1 .. y0+4); ry=6
// zeroed (read by q=3,r=3 with A-weight 0); ry=7 unused. Output row r
// reads slot s*8+q+r (q+r <= 6). Pitch 25 cells (400 B).
constexpr int PKQ = 25;
constexpr int XT  = 130;  // staged x extent: x = -1 .. 128

typedef short bf16x8 __attribute__((ext_vector_type(8)));  // 8 bf16 = 4 VGPR
typedef float f32x4  __attribute__((ext_vector_type(4)));

__device__ inline unsigned short f2b(float f) {
  __hip_bfloat16 h = __float2bfloat16(f);
  return *(unsigned short*)&h;
}
__device__ inline float b2f(unsigned short u) {
  __hip_bfloat16 h = *(__hip_bfloat16*)&u;
  return __bfloat162float(h);
}

// ---------------------------------------------------------------------------
// Prep: pack w1/w2 into MFMA A-fragment order, bf16, dx-split.
// A-weight for k-group (s,q): w(dz=s, dy=q), zero at q=3 — unchanged by the
// y-quad B-slot re-pitch (A layout depends only on (lane,j)).
// Tail zero-fills 32-B guards around ti/xi (adapt x-halo reads).
// ---------------------------------------------------------------------------
__global__ __launch_bounds__(256) void k_prep(
    const float* __restrict__ w1, const float* __restrict__ w2,
    unsigned short* __restrict__ Wpack2, unsigned short* __restrict__ Wpack1,
    float* __restrict__ g_ti, float* __restrict__ g_xi) {
  int i = blockIdx.x * 256 + threadIdx.x;
  if (i < 9216) {
    int j = i & 7;
    int lane = (i >> 3) & 63;
    int Mt = (i >> 9) & 1;
    int g2 = i >> 10;         // dx*3 + s
    int s = g2 % 3, dx = g2 / 3;
    int oc = Mt * 16 + (lane & 15);
    int kr = s * 32 + (lane >> 4) * 8 + j;
    int ci = kr & 7, g = kr >> 3;          // g = s*4 + q
    float w = 0.f;
    if (oc < 27 && (g & 3) < 3) {
      int dzr = g >> 2, dyr = g & 3;
      w = w2[(oc * 8 + ci) * 27 + dzr * 9 + dyr * 3 + dx];
    }
    Wpack2[i] = f2b(w);
  }
  int jj = i - 9216;
  if (jj >= 0 && jj < 4608) {
    int j = jj & 7;
    int lane = (jj >> 3) & 63;
    int g2 = jj >> 9;         // dx*3 + s
    int s = g2 % 3, dx = g2 / 3;
    int oc = lane & 15;
    int kr = s * 32 + (lane >> 4) * 8 + j;
    int ci = kr & 7, g = kr >> 3;
    float w = 0.f;
    if (oc < 8 && (g & 3) < 3) {
      int dzr = g >> 2, dyr = g & 3;
      w = w1[(oc * 8 + ci) * 27 + dzr * 9 + dyr * 3 + dx];
    }
    Wpack1[jj] = f2b(w);
  }
  int gg = i - 13824;
  if (gg >= 0 && gg < 32) {
    float* p = (gg < 8)  ? (g_ti - 8 + gg)
             : (gg < 16) ? (g_ti + (size_t)8 * DHW + (gg - 8))
             : (gg < 24) ? (g_xi - 8 + (gg - 16))
                         : (g_xi + (size_t)8 * DHW + (gg - 24));
    *p = 0.f;
  }
}

// ---------------------------------------------------------------------------
// Transpose x: [ci][z][y][x] fp32 -> [z][y][x][ci] bf16 (xb, for conv1 MFMA)
//                                 and [z][y][x][ci] fp32 (xi, for adapt pass)
// ---------------------------------------------------------------------------
__global__ __launch_bounds__(256) void k_xpose(
    const float* __restrict__ x, unsigned short* __restrict__ xb,
    float* __restrict__ xi) {
  int idx = blockIdx.x * 256 + threadIdx.x;  // voxel
  float f[8];
  unsigned v[4];
#pragma unroll
  for (int p = 0; p < 4; ++p) {
    f[2 * p]     = x[(size_t)(2 * p) * DHW + idx];
    f[2 * p + 1] = x[(size_t)(2 * p + 1) * DHW + idx];
    unsigned lo = f2b(f[2 * p]);
    unsigned hi = f2b(f[2 * p + 1]);
    v[p] = lo | (hi << 16);
  }
  ((uint4*)xb)[idx] = make_uint4(v[0], v[1], v[2], v[3]);
  float4* xo = (float4*)(xi + (size_t)idx * 8);
  xo[0] = make_float4(f[0], f[1], f[2], f[3]);
  xo[1] = make_float4(f[4], f[5], f[6], f[7]);
}

// ---------------------------------------------------------------------------
// Conv staging (R14 y-quad): 18 real rows (dz 0..2 x ry 0..5) x 128 interior
// cols = 9 exact rounds, batched (MLP 9), division only on tiny row index.
// Zero tasks: ry=6 slots (3 x 130) + x-halo cells (xi 0,129) for read slots.
// ---------------------------------------------------------------------------
#define STAGE_QUAD(srcp)                                                   \
  {                                                                        \
    if (tid < 195) {                                                       \
      _Pragma("unroll")                                                    \
      for (int k = 0; k < 2; ++k) {                                        \
        const int c = tid * 2 + k;  /* < 390 */                            \
        const int dzz = c / 130;                                           \
        const int xih = c - 130 * dzz;                                     \
        dst[xih * PKQ + dzz * 8 + 6] = make_uint4(0u, 0u, 0u, 0u);         \
      }                                                                    \
    }                                                                      \
    if (tid < 36) {                                                        \
      const int sl = tid >> 1;            /* 0..17 */                      \
      const int dzz = sl / 6, ryy = sl - 6 * dzz;                          \
      const int xih = (tid & 1) ? 129 : 0;                                 \
      dst[xih * PKQ + dzz * 8 + ryy] = make_uint4(0u, 0u, 0u, 0u);         \
    }                                                                      \
    const int th_ = tid >> 7;                                              \
    const int col_ = tid & 127;                                            \
    const int xi_ = col_ + 1;                                              \
    uint4 sv[9];                                                           \
    bool vld[9];                                                           \
    _Pragma("unroll")                                                      \
    for (int it = 0; it < 9; ++it) {                                       \
      const int row = 2 * it + th_;       /* 0..17 */                      \
      const int dzz = row / 6, ryy = row - 6 * dzz;                        \
      const int z = z0 + dzz - 1, y = y0 + ryy - 1;                        \
      vld[it] = ((unsigned)z < 128u) & ((unsigned)y < 128u);               \
      const int zz = vld[it] ? z : z0, yy = vld[it] ? y : y0;              \
      sv[it] = (srcp)[(zz * 128 + yy) * 128 + col_];                       \
    }                                                                      \
    _Pragma("unroll")                                                      \
    for (int it = 0; it < 9; ++it) {                                       \
      const int row = 2 * it + th_;                                        \
      const int dzz = row / 6, ryy = row - 6 * dzz;                        \
      uint4 v = vld[it] ? sv[it] : make_uint4(0u, 0u, 0u, 0u);             \
      dst[xi_ * PKQ + dzz * 8 + ryy] = v;                                  \
    }                                                                      \
  }

// ---------------------------------------------------------------------------
// Kernel 1: conv3d(x, w1) + bias + ReLU (8 -> 8), implicit-GEMM MFMA.
// y-quad per block; grid 128 z * 32 yquads = 4096. LDS 52 KB -> 3 blocks/CU.
// ---------------------------------------------------------------------------
__global__ __launch_bounds__(256, 3) void k_conv1m(
    const unsigned short* __restrict__ xb,
    const unsigned short* __restrict__ Wpack1,
    const float* __restrict__ b1, unsigned short* __restrict__ hb) {
  __shared__ __align__(16) unsigned short T[XT * PKQ * 8];
  const int tid  = threadIdx.x;
  const int lane = tid & 63;
  const int wv   = tid >> 6;
  // XCD-chunked bijective swizzle (4096 % 8 == 0), chunk 512.
  const int logical = (blockIdx.x & 7) * 512 + (blockIdx.x >> 3);
  const int z0 = logical >> 5;
  const int y0 = (logical & 31) * 4;

  bf16x8 wf[3][3];
  {
    const bf16x8* wp = (const bf16x8*)Wpack1;
#pragma unroll
    for (int dx = 0; dx < 3; ++dx)
#pragma unroll
      for (int s = 0; s < 3; ++s)
        wf[dx][s] = wp[(dx * 3 + s) * 64 + lane];
  }

  const uint4* src = (const uint4*)xb;
  uint4* dst = (uint4*)T;
  STAGE_QUAD(src);
  __syncthreads();

  f32x4 acc[4][2];  // [r][nt]
#pragma unroll
  for (int r = 0; r < 4; ++r)
#pragma unroll
    for (int nt = 0; nt < 2; ++nt) acc[r][nt] = (f32x4){0.f, 0.f, 0.f, 0.f};

  const int n = lane & 15;
  const int q = lane >> 4;
  const int xbase = wv * 32 + n;

#pragma unroll
  for (int dx = 0; dx < 3; ++dx) {
#pragma unroll
    for (int s = 0; s < 3; ++s) {
      bf16x8 bfr[4][2];
#pragma unroll
      for (int r = 0; r < 4; ++r)
#pragma unroll
        for (int nt = 0; nt < 2; ++nt) {
          int off = ((xbase + nt * 16 + dx) * PKQ + (s * 8 + q + r)) * 8;
          bfr[r][nt] = *(const bf16x8*)&T[off];
        }
#pragma unroll
      for (int r = 0; r < 4; ++r)
#pragma unroll
        for (int nt = 0; nt < 2; ++nt)
          acc[r][nt] = __builtin_amdgcn_mfma_f32_16x16x32_bf16(
              wf[dx][s], bfr[r][nt], acc[r][nt], 0, 0, 0);
    }
  }

  if (q < 2) {
#pragma unroll
    for (int r = 0; r < 4; ++r) {
      const int voxrow = (z0 * 128 + y0 + r) * 128;
#pragma unroll
      for (int nt = 0; nt < 2; ++nt) {
        const int vox = voxrow + wv * 32 + nt * 16 + n;
        ushort4 o;
        o.x = f2b(fmaxf(acc[r][nt][0] + b1[q * 4 + 0], 0.f));
        o.y = f2b(fmaxf(acc[r][nt][1] + b1[q * 4 + 1], 0.f));
        o.z = f2b(fmaxf(acc[r][nt][2] + b1[q * 4 + 2], 0.f));
        o.w = f2b(fmaxf(acc[r][nt][3] + b1[q * 4 + 3], 0.f));
        *(ushort4*)(hb + (size_t)vox * 8 + q * 4) = o;
      }
    }
  }
}

// ---------------------------------------------------------------------------
// Kernel 2: conv3d(h, w2) (8 -> 27) + fused L1 norm, implicit-GEMM MFMA.
// y-quad per block; grid 4096. wf reloaded per-dx (24 live VGPR instead of
// 72, L1-hot) to stay under the 170-VGPR cap for 3 waves/SIMD.
// ---------------------------------------------------------------------------
__global__ __launch_bounds__(256, 3) void k_conv2(
    const unsigned short* __restrict__ hb,
    const unsigned short* __restrict__ Wpack2,
    unsigned short* __restrict__ wn) {
  __shared__ __align__(16) unsigned short T[XT * PKQ * 8];
  const int tid  = threadIdx.x;
  const int lane = tid & 63;
  const int wv   = tid >> 6;
  const int logical = (blockIdx.x & 7) * 512 + (blockIdx.x >> 3);
  const int z0 = logical >> 5;
  const int y0 = (logical & 31) * 4;

  const uint4* src = (const uint4*)hb;
  uint4* dst = (uint4*)T;
  STAGE_QUAD(src);
  __syncthreads();

  f32x4 acc[4][2][2];  // [r][nt][mt]
#pragma unroll
  for (int r = 0; r < 4; ++r)
#pragma unroll
    for (int nt = 0; nt < 2; ++nt)
#pragma unroll
      for (int mt = 0; mt < 2; ++mt)
        acc[r][nt][mt] = (f32x4){0.f, 0.f, 0.f, 0.f};

  const int n = lane & 15;
  const int q = lane >> 4;
  const int xbase = wv * 32 + n;
  const bf16x8* wp = (const bf16x8*)Wpack2;

#pragma unroll
  for (int dx = 0; dx < 3; ++dx) {
    bf16x8 wf[3][2];
#pragma unroll
    for (int s = 0; s < 3; ++s)
#pragma unroll
      for (int mt = 0; mt < 2; ++mt)
        wf[s][mt] = wp[((dx * 3 + s) * 2 + mt) * 64 + lane];
#pragma unroll
    for (int s = 0; s < 3; ++s) {
      bf16x8 bfr[4][2];
#pragma unroll
      for (int r = 0; r < 4; ++r)
#pragma unroll
        for (int nt = 0; nt < 2; ++nt) {
          int off = ((xbase + nt * 16 + dx) * PKQ + (s * 8 + q + r)) * 8;
          bfr[r][nt] = *(const bf16x8*)&T[off];
        }
#pragma unroll
      for (int r = 0; r < 4; ++r)
#pragma unroll
        for (int mt = 0; mt < 2; ++mt)
#pragma unroll
          for (int nt = 0; nt < 2; ++nt)
            acc[r][nt][mt] = __builtin_amdgcn_mfma_f32_16x16x32_bf16(
                wf[s][mt], bfr[r][nt], acc[r][nt][mt], 0, 0, 0);
    }
  }

#pragma unroll
  for (int r = 0; r < 4; ++r) {
    const int voxrow = (z0 * 128 + y0 + r) * 128;
#pragma unroll
    for (int nt = 0; nt < 2; ++nt) {
      float ns = 0.f;
#pragma unroll
      for (int rr = 0; rr < 4; ++rr) ns += fabsf(acc[r][nt][0][rr]);
#pragma unroll
      for (int rr = 0; rr < 4; ++rr) {
        int oc = 16 + q * 4 + rr;
        ns += (oc < 27) ? fabsf(acc[r][nt][1][rr]) : 0.f;
      }
      ns += __shfl_xor(ns, 16);
      ns += __shfl_xor(ns, 32);
      float sc = 1.f / fmaxf(ns, 1e-12f);
      const int vox = voxrow + wv * 32 + nt * 16 + n;
#pragma unroll
      for (int rr = 0; rr < 4; ++rr) {
        int oc = q * 4 + rr;
        wn[(size_t)oc * DHW + vox] = f2b(acc[r][nt][0][rr] * sc);
      }
#pragma unroll
      for (int rr = 0; rr < 4; ++rr) {
        int oc = 16 + q * 4 + rr;
        if (oc < 27)
          wn[(size_t)oc * DHW + vox] = f2b(acc[r][nt][1][rr] * sc);
      }
    }
  }
}

// ---------------------------------------------------------------------------
// Kernel 3 (R12-proven, reverted from R13): quad-tiled adaptive conv.
// R13's wn dz-ping-pong regressed (VGPR 120->176, occupancy halved, 82 us);
// this R12 body measured 60 us/pass, FETCH 104 / WRITE 64 MB, no spill.
// ---------------------------------------------------------------------------
constexpr int APITCH = 2112;  // 66 slots * 32 B
__device__ inline int swz7(int off) { return off ^ (((off >> 7) & 7) << 4); }

template <int FINAL>
__global__ __launch_bounds__(256, 1) void k_adapt8(
    const float* __restrict__ in, const unsigned short* __restrict__ wn,
    float* __restrict__ out) {
  __shared__ __align__(16) char S[36 * APITCH];  // 76032 B
  const int tid = threadIdx.x;
  // grid 2048; XCD-chunked bijective swizzle, chunk 256.
  const int logical = (blockIdx.x & 7) * 256 + (blockIdx.x >> 3);
  const int xh  = logical & 1;
  const int typ = (logical >> 1) & 31;
  const int tzp = logical >> 6;
  const int x0 = xh * 64, y0 = typ * 4, z0 = tzp * 4;

  // ---- staging: interior (x = x0..x0+63): 36 rows x 128 uint4.
  const int th = tid >> 7;        // 0/1
  const int kcol = tid & 127;
  const int wbyte = swz7(32 + kcol * 16);
#pragma unroll 1
  for (int ib = 0; ib < 2; ++ib) {  // two batches of 9 rounds (MLP 9)
    uint4 stg[9];
#pragma unroll
    for (int i = 0; i < 9; ++i) {
      const int r = 2 * (ib * 9 + i) + th;
      const int r6 = r / 6;
      const int zs = min(max(z0 - 1 + r6, 0), 127);
      const int ys = min(max(y0 - 1 + (r - r6 * 6), 0), 127);
      stg[i] = *(const uint4*)(in + (size_t)(zs * 128 + ys) * 1024 +
                               x0 * 8 + kcol * 4);
    }
#pragma unroll
    for (int i = 0; i < 9; ++i) {
      const int r = 2 * (ib * 9 + i) + th;
      *(uint4*)(S + r * APITCH + wbyte) = stg[i];
    }
  }
  // ---- halo columns: slot 0 (x0-1) and slot 65 (x0+64); 144 threads.
  if (tid < 144) {
    const int hr = tid >> 2;        // row 0..35
    const int hp = tid & 3;         // 0,1 -> slot 0 halves; 2,3 -> slot 65
    const int r6 = hr / 6;
    const int zs = min(max(z0 - 1 + r6, 0), 127);
    const int ys = min(max(y0 - 1 + (hr - r6 * 6), 0), 127);
    const int fo = (hp < 2) ? ((x0 - 1) * 8 + hp * 4)
                            : ((x0 + 64) * 8 + (hp - 2) * 4);
    uint4 v = *(const uint4*)(in + (size_t)(zs * 128 + ys) * 1024 + fo);
    const bool zero = xh ? (hp >= 2) : (hp < 2);  // global x=-1 / x=128
    if (zero) v = make_uint4(0u, 0u, 0u, 0u);
    const int sb = (hp < 2) ? (hp * 16) : (65 * 32 + (hp - 2) * 16);
    *(uint4*)(S + hr * APITCH + swz7(sb)) = v;
  }
  __syncthreads();

  // ---- compute: thread = (xp, yp, zo) -> 2x*2y quad ----
  const int xp = tid & 31;
  const int yp = (tid >> 5) & 1;
  const int zo = tid >> 6;
  const int Y = y0 + 2 * yp;
  const int Z = z0 + zo;

  unsigned zokm = 0;
#pragma unroll
  for (int d = 0; d < 3; ++d)
    zokm |= ((unsigned)(Z + d - 1) < 128u) ? (1u << d) : 0u;
  bool yok[2][3];
#pragma unroll
  for (int oy = 0; oy < 2; ++oy)
#pragma unroll
    for (int d = 0; d < 3; ++d)
      yok[oy][d] = (unsigned)(Y + oy + d - 1) < 128u;

  int soff[4][2];
#pragma unroll
  for (int j = 0; j < 4; ++j)
#pragma unroll
    for (int h = 0; h < 2; ++h)
      soff[j][h] = swz7((2 * xp + j) * 32 + h * 16);

  const size_t voxp0 = (size_t)(Z * 128 + Y) * 128 + x0 + 2 * xp;

  f32x4 acc[2][2][2];  // [oy][ox][h], all-static indexing
#pragma unroll
  for (int oy = 0; oy < 2; ++oy)
#pragma unroll
    for (int ox = 0; ox < 2; ++ox)
#pragma unroll
      for (int h = 0; h < 2; ++h)
        acc[oy][ox][h] = (f32x4){0.f, 0.f, 0.f, 0.f};

#pragma unroll 1
  for (int dz = 0; dz < 3; ++dz) {
    const char* Rz = S + ((zo + dz) * 6 + 2 * yp) * APITCH;
    const unsigned short* wz = wn + (size_t)dz * 9 * DHW;
    const bool zv = (zokm >> dz) & 1u;
#pragma unroll
    for (int yr = 0; yr < 4; ++yr) {
      const char* R = Rz + yr * APITCH;
      f32x4 W[4][2];
#pragma unroll
      for (int j = 0; j < 4; ++j)
#pragma unroll
        for (int h = 0; h < 2; ++h)
          W[j][h] = *(const f32x4*)(R + soff[j][h]);
#pragma unroll
      for (int oy = 0; oy < 2; ++oy) {
        const int dy = yr - oy;
        if (dy >= 0 && dy < 3) {
          const bool val = zv && yok[oy][dy];
          const size_t voxp = voxp0 + (size_t)oy * 128;
#pragma unroll
          for (int dxi = 0; dxi < 3; ++dxi) {
            const unsigned u = *(const unsigned*)(
                wz + (size_t)(dy * 3 + dxi) * DHW + voxp);
            const float w0 = val ? b2f((unsigned short)(u & 0xffffu)) : 0.f;
            const float w1 = val ? b2f((unsigned short)(u >> 16)) : 0.f;
#pragma unroll
            for (int h = 0; h < 2; ++h)
#pragma unroll
              for (int c = 0; c < 4; ++c) {
                acc[oy][0][h][c] = fmaf(W[dxi][h][c], w0, acc[oy][0][h][c]);
                acc[oy][1][h][c] =
                    fmaf(W[dxi + 1][h][c], w1, acc[oy][1][h][c]);
              }
          }
        }
      }
    }
  }

  if (FINAL) {
    // planar fp32 [c][vox] -> d_out; float2 = x-pair
#pragma unroll
    for (int oy = 0; oy < 2; ++oy) {
      const size_t voxp = voxp0 + (size_t)oy * 128;
#pragma unroll
      for (int h = 0; h < 2; ++h)
#pragma unroll
        for (int c = 0; c < 4; ++c) {
          float2 o = make_float2(acc[oy][0][h][c], acc[oy][1][h][c]);
          *(float2*)(out + (size_t)(h * 4 + c) * DHW + voxp) = o;
        }
    }
  } else {
    // interleaved fp32 [vox][8]; 64 B contiguous per thread per y
#pragma unroll
    for (int oy = 0; oy < 2; ++oy) {
      const size_t voxp = voxp0 + (size_t)oy * 128;
      f32x4* op = (f32x4*)(out + voxp * 8);
      op[0] = acc[oy][0][0];
      op[1] = acc[oy][0][1];
      op[2] = acc[oy][1][0];
      op[3] = acc[oy][1][1];
    }
  }
}

// ---------------------------------------------------------------------------
extern "C" void kernel_launch(void* const* d_in, const int* in_sizes, int n_in,
                              void* d_out, int out_size, void* d_ws, size_t ws_size,
                              hipStream_t stream) {
  const float* x  = (const float*)d_in[0];
  const float* w1 = (const float*)d_in[1];
  const float* b1 = (const float*)d_in[2];
  const float* w2 = (const float*)d_in[3];
  float* out = (float*)d_out;

  // Workspace (~236 MiB + pads):
  //   [0,   64M): xb(32M)+hb(32M) bf16; reused as ti = ws+256 (64M fp32)
  //   [64M+4K, 172M+4K): wn bf16 planar (27 x DHW)
  //   [172M+12K, 236M+12K): xi fp32 interleaved
  //   then Wpack2, Wpack1. Guard zeros at ti/xi +-32 B (k_prep tail).
  char* ws = (char*)d_ws;
  unsigned short* xb = (unsigned short*)ws;
  unsigned short* hb = (unsigned short*)(ws + (size_t)8 * DHW * 2);
  float* ti = (float*)(ws + 256);  // aliases xb+hb (both dead before adapt)
  unsigned short* wn = (unsigned short*)(ws + (size_t)16 * DHW * 2 + 4096);
  float* xi = (float*)(ws + (size_t)16 * DHW * 2 + 4096 +
                       (size_t)27 * DHW * 2 + 8192);
  unsigned short* Wpack2 =
      (unsigned short*)((char*)xi + (size_t)8 * DHW * 4 + 16384);
  unsigned short* Wpack1 = Wpack2 + 9216;

  dim3 blk(256);
  k_prep<<<55, blk, 0, stream>>>(w1, w2, Wpack2, Wpack1, ti, xi);
  k_xpose<<<DHW / 256, blk, 0, stream>>>(x, xb, xi);
  k_conv1m<<<128 * 32, blk, 0, stream>>>(xb, Wpack1, b1, hb);
  k_conv2<<<128 * 32, blk, 0, stream>>>(hb, Wpack2, wn);
  // adaptive ping-pong on interleaved fp32: xi -> ti -> xi -> out (planar)
  k_adapt8<0><<<2048, blk, 0, stream>>>(xi, wn, ti);
  k_adapt8<0><<<2048, blk, 0, stream>>>(ti, wn, xi);
  k_adapt8<1><<<2048, blk, 0, stream>>>(xi, wn, out);
}

// Round 15
// 360.112 us; speedup vs baseline: 1.1494x; 1.0084x over previous
//
#include <hip/hip_runtime.h>
#include <hip/hip_bf16.h>

// Geometry (fixed): B=1, C=8, D=H=W=128.
constexpr int HW2 = 16384;
constexpr int DHW = 2097152;

// MFMA staging: LDS cell = 8 ci (bf16, 16 B) at (slot = dz*4+ry, xi).
constexpr int PKG = 13;
constexpr int XT  = 130;  // staged x extent: x = -1 .. 128

typedef short bf16x8 __attribute__((ext_vector_type(8)));  // 8 bf16 = 4 VGPR
typedef float f32x4  __attribute__((ext_vector_type(4)));

__device__ inline unsigned short f2b(float f) {
  __hip_bfloat16 h = __float2bfloat16(f);
  return *(unsigned short*)&h;
}
__device__ inline float b2f(unsigned short u) {
  __hip_bfloat16 h = *(__hip_bfloat16*)&u;
  return __bfloat162float(h);
}

// ---------------------------------------------------------------------------
// Prep: pack w1/w2 into MFMA A-fragment order, bf16, dx-split.
// Slot g = s*4+q interpreted as (dz = g>>2 = s, dy = g&3 = q); dy==3 -> 0.
// Tail zero-fills 32-B guards around ti/xi (adapt x-halo reads).
// ---------------------------------------------------------------------------
__global__ __launch_bounds__(256) void k_prep(
    const float* __restrict__ w1, const float* __restrict__ w2,
    unsigned short* __restrict__ Wpack2, unsigned short* __restrict__ Wpack1,
    float* __restrict__ g_ti, float* __restrict__ g_xi) {
  int i = blockIdx.x * 256 + threadIdx.x;
  if (i < 9216) {
    int j = i & 7;
    int lane = (i >> 3) & 63;
    int Mt = (i >> 9) & 1;
    int g2 = i >> 10;         // dx*3 + s
    int s = g2 % 3, dx = g2 / 3;
    int oc = Mt * 16 + (lane & 15);
    int kr = s * 32 + (lane >> 4) * 8 + j;
    int ci = kr & 7, g = kr >> 3;          // g = s*4 + q
    float w = 0.f;
    if (oc < 27 && (g & 3) < 3) {
      int dzr = g >> 2, dyr = g & 3;
      w = w2[(oc * 8 + ci) * 27 + dzr * 9 + dyr * 3 + dx];
    }
    Wpack2[i] = f2b(w);
  }
  int jj = i - 9216;
  if (jj >= 0 && jj < 4608) {
    int j = jj & 7;
    int lane = (jj >> 3) & 63;
    int g2 = jj >> 9;         // dx*3 + s
    int s = g2 % 3, dx = g2 / 3;
    int oc = lane & 15;
    int kr = s * 32 + (lane >> 4) * 8 + j;
    int ci = kr & 7, g = kr >> 3;
    float w = 0.f;
    if (oc < 8 && (g & 3) < 3) {
      int dzr = g >> 2, dyr = g & 3;
      w = w1[(oc * 8 + ci) * 27 + dzr * 9 + dyr * 3 + dx];
    }
    Wpack1[jj] = f2b(w);
  }
  int gg = i - 13824;
  if (gg >= 0 && gg < 32) {
    float* p = (gg < 8)  ? (g_ti - 8 + gg)
             : (gg < 16) ? (g_ti + (size_t)8 * DHW + (gg - 8))
             : (gg < 24) ? (g_xi - 8 + (gg - 16))
                         : (g_xi + (size_t)8 * DHW + (gg - 24));
    *p = 0.f;
  }
}

// ---------------------------------------------------------------------------
// Transpose x: [ci][z][y][x] fp32 -> [z][y][x][ci] bf16 (xb, for conv1 MFMA)
//                                 and [z][y][x][ci] fp32 (xi, for adapt pass)
// ---------------------------------------------------------------------------
__global__ __launch_bounds__(256) void k_xpose(
    const float* __restrict__ x, unsigned short* __restrict__ xb,
    float* __restrict__ xi) {
  int idx = blockIdx.x * 256 + threadIdx.x;  // voxel
  float f[8];
  unsigned v[4];
#pragma unroll
  for (int p = 0; p < 4; ++p) {
    f[2 * p]     = x[(size_t)(2 * p) * DHW + idx];
    f[2 * p + 1] = x[(size_t)(2 * p + 1) * DHW + idx];
    unsigned lo = f2b(f[2 * p]);
    unsigned hi = f2b(f[2 * p + 1]);
    v[p] = lo | (hi << 16);
  }
  ((uint4*)xb)[idx] = make_uint4(v[0], v[1], v[2], v[3]);
  float4* xo = (float4*)(xi + (size_t)idx * 8);
  xo[0] = make_float4(f[0], f[1], f[2], f[3]);
  xo[1] = make_float4(f[4], f[5], f[6], f[7]);
}

// ---------------------------------------------------------------------------
// Shared conv staging (R7 y-pair, proven): batched-MLP, division-free.
// ---------------------------------------------------------------------------
#define STAGE_ROWS2(srcp)                                                  \
  {                                                                        \
    if (tid < 154) {                                                       \
      if (tid < 130) {                                                     \
        dst[tid * PKG + 12] = make_uint4(0u, 0u, 0u, 0u);                  \
      } else {                                                             \
        int k = tid - 130;                                                 \
        int sl = k >> 1, xih = (k & 1) ? 129 : 0;                          \
        dst[xih * PKG + sl] = make_uint4(0u, 0u, 0u, 0u);                  \
      }                                                                    \
    }                                                                      \
    const int gg = tid >> 7;                                               \
    const int xi_ = (tid & 127) + 1;                                       \
    const int xg_ = xi_ - 1;                                               \
    uint4 sv[6];                                                           \
    bool vld[6];                                                           \
    _Pragma("unroll")                                                      \
    for (int it = 0; it < 6; ++it) {                                       \
      const int g = gg + it * 2;                                           \
      const int dz = g >> 2, ry = g & 3;                                   \
      const int z = z0 + dz - 1, y = y0 + ry - 1;                          \
      vld[it] = ((unsigned)z < 128u) & ((unsigned)y < 128u);               \
      const int zz = vld[it] ? z : z0, yy = vld[it] ? y : y0;              \
      sv[it] = (srcp)[(zz * 128 + yy) * 128 + xg_];                        \
    }                                                                      \
    _Pragma("unroll")                                                      \
    for (int it = 0; it < 6; ++it) {                                       \
      const int g = gg + it * 2;                                           \
      uint4 v = vld[it] ? sv[it] : make_uint4(0u, 0u, 0u, 0u);             \
      dst[xi_ * PKG + g] = v;                                              \
    }                                                                      \
  }

// ---------------------------------------------------------------------------
// Kernel 1: conv3d(x, w1) + bias + ReLU (8 -> 8), implicit-GEMM MFMA.
// y-pair per block; grid 128 z * 64 ypairs = 8192.
// ---------------------------------------------------------------------------
__global__ __launch_bounds__(256, 3) void k_conv1m(
    const unsigned short* __restrict__ xb,
    const unsigned short* __restrict__ Wpack1,
    const float* __restrict__ b1, unsigned short* __restrict__ hb) {
  __shared__ __align__(16) unsigned short T[XT * PKG * 8];
  const int tid  = threadIdx.x;
  const int lane = tid & 63;
  const int wv   = tid >> 6;
  const int logical = (blockIdx.x & 7) * 1024 + (blockIdx.x >> 3);
  const int z0 = logical >> 6;
  const int y0 = (logical & 63) * 2;

  bf16x8 wf[3][3];
  {
    const bf16x8* wp = (const bf16x8*)Wpack1;
#pragma unroll
    for (int dx = 0; dx < 3; ++dx)
#pragma unroll
      for (int s = 0; s < 3; ++s)
        wf[dx][s] = wp[(dx * 3 + s) * 64 + lane];
  }

  const uint4* src = (const uint4*)xb;
  uint4* dst = (uint4*)T;
  STAGE_ROWS2(src);
  __syncthreads();

  f32x4 acc[2][2];  // [r][nt]
#pragma unroll
  for (int r = 0; r < 2; ++r)
#pragma unroll
    for (int nt = 0; nt < 2; ++nt) acc[r][nt] = (f32x4){0.f, 0.f, 0.f, 0.f};

  const int n = lane & 15;
  const int q = lane >> 4;
  const int xbase = wv * 32 + n;

#pragma unroll
  for (int dx = 0; dx < 3; ++dx) {
#pragma unroll
    for (int s = 0; s < 3; ++s) {
      bf16x8 bfr[2][2];
#pragma unroll
      for (int r = 0; r < 2; ++r)
#pragma unroll
        for (int nt = 0; nt < 2; ++nt) {
          int off = ((xbase + nt * 16 + dx) * PKG + (s * 4 + q + r)) * 8;
          bfr[r][nt] = *(const bf16x8*)&T[off];
        }
#pragma unroll
      for (int r = 0; r < 2; ++r)
#pragma unroll
        for (int nt = 0; nt < 2; ++nt)
          acc[r][nt] = __builtin_amdgcn_mfma_f32_16x16x32_bf16(
              wf[dx][s], bfr[r][nt], acc[r][nt], 0, 0, 0);
    }
  }

  if (q < 2) {
#pragma unroll
    for (int r = 0; r < 2; ++r) {
      const int voxrow = (z0 * 128 + y0 + r) * 128;
#pragma unroll
      for (int nt = 0; nt < 2; ++nt) {
        const int vox = voxrow + wv * 32 + nt * 16 + n;
        ushort4 o;
        o.x = f2b(fmaxf(acc[r][nt][0] + b1[q * 4 + 0], 0.f));
        o.y = f2b(fmaxf(acc[r][nt][1] + b1[q * 4 + 1], 0.f));
        o.z = f2b(fmaxf(acc[r][nt][2] + b1[q * 4 + 2], 0.f));
        o.w = f2b(fmaxf(acc[r][nt][3] + b1[q * 4 + 3], 0.f));
        *(ushort4*)(hb + (size_t)vox * 8 + q * 4) = o;
      }
    }
  }
}

// ---------------------------------------------------------------------------
// Kernel 2: conv3d(h, w2) (8 -> 27) + fused L1 norm, implicit-GEMM MFMA.
// y-pair per block; grid 8192.
// ---------------------------------------------------------------------------
__global__ __launch_bounds__(256, 2) void k_conv2(
    const unsigned short* __restrict__ hb,
    const unsigned short* __restrict__ Wpack2,
    unsigned short* __restrict__ wn) {
  __shared__ __align__(16) unsigned short T[XT * PKG * 8];
  const int tid  = threadIdx.x;
  const int lane = tid & 63;
  const int wv   = tid >> 6;
  const int logical = (blockIdx.x & 7) * 1024 + (blockIdx.x >> 3);
  const int z0 = logical >> 6;
  const int y0 = (logical & 63) * 2;

  bf16x8 wf[3][3][2];
  {
    const bf16x8* wp = (const bf16x8*)Wpack2;
#pragma unroll
    for (int dx = 0; dx < 3; ++dx)
#pragma unroll
      for (int s = 0; s < 3; ++s)
#pragma unroll
        for (int mt = 0; mt < 2; ++mt)
          wf[dx][s][mt] = wp[((dx * 3 + s) * 2 + mt) * 64 + lane];
  }

  const uint4* src = (const uint4*)hb;
  uint4* dst = (uint4*)T;
  STAGE_ROWS2(src);
  __syncthreads();

  f32x4 acc[2][2][2];  // [r][nt][mt]
#pragma unroll
  for (int r = 0; r < 2; ++r)
#pragma unroll
    for (int nt = 0; nt < 2; ++nt)
#pragma unroll
      for (int mt = 0; mt < 2; ++mt)
        acc[r][nt][mt] = (f32x4){0.f, 0.f, 0.f, 0.f};

  const int n = lane & 15;
  const int q = lane >> 4;
  const int xbase = wv * 32 + n;

#pragma unroll
  for (int dx = 0; dx < 3; ++dx) {
#pragma unroll
    for (int s = 0; s < 3; ++s) {
      bf16x8 bfr[2][2];
#pragma unroll
      for (int r = 0; r < 2; ++r)
#pragma unroll
        for (int nt = 0; nt < 2; ++nt) {
          int off = ((xbase + nt * 16 + dx) * PKG + (s * 4 + q + r)) * 8;
          bfr[r][nt] = *(const bf16x8*)&T[off];
        }
#pragma unroll
      for (int r = 0; r < 2; ++r)
#pragma unroll
        for (int mt = 0; mt < 2; ++mt)
#pragma unroll
          for (int nt = 0; nt < 2; ++nt)
            acc[r][nt][mt] = __builtin_amdgcn_mfma_f32_16x16x32_bf16(
                wf[dx][s][mt], bfr[r][nt], acc[r][nt][mt], 0, 0, 0);
    }
  }

#pragma unroll
  for (int r = 0; r < 2; ++r) {
    const int voxrow = (z0 * 128 + y0 + r) * 128;
#pragma unroll
    for (int nt = 0; nt < 2; ++nt) {
      float ns = 0.f;
#pragma unroll
      for (int rr = 0; rr < 4; ++rr) ns += fabsf(acc[r][nt][0][rr]);
#pragma unroll
      for (int rr = 0; rr < 4; ++rr) {
        int oc = 16 + q * 4 + rr;
        ns += (oc < 27) ? fabsf(acc[r][nt][1][rr]) : 0.f;
      }
      ns += __shfl_xor(ns, 16);
      ns += __shfl_xor(ns, 32);
      float sc = 1.f / fmaxf(ns, 1e-12f);
      const int vox = voxrow + wv * 32 + nt * 16 + n;
#pragma unroll
      for (int rr = 0; rr < 4; ++rr) {
        int oc = q * 4 + rr;
        wn[(size_t)oc * DHW + vox] = f2b(acc[r][nt][0][rr] * sc);
      }
#pragma unroll
      for (int rr = 0; rr < 4; ++rr) {
        int oc = 16 + q * 4 + rr;
        if (oc < 27)
          wn[(size_t)oc * DHW + vox] = f2b(acc[r][nt][1][rr] * sc);
      }
    }
  }
}

// ---------------------------------------------------------------------------
// Kernel 3 (R12-proven): quad-tiled adaptive conv, spill-proofed.
// Tile 64x*4y*4z; window 36 rows x 66 slots = 74.25 KiB -> 2 blocks/CU.
// Thread = 2x*2y quad -> 24 b128 LDS reads/vox. Measured: 57-60 us/pass,
// VGPR 120, FETCH 104 / WRITE 64 MB (no spill), conflicts 3.7M.
// R13's deeper wn pipelining regressed (occupancy halved) — keep as-is.
// ---------------------------------------------------------------------------
constexpr int APITCH = 2112;  // 66 slots * 32 B
__device__ inline int swz7(int off) { return off ^ (((off >> 7) & 7) << 4); }

template <int FINAL>
__global__ __launch_bounds__(256, 1) void k_adapt8(
    const float* __restrict__ in, const unsigned short* __restrict__ wn,
    float* __restrict__ out) {
  __shared__ __align__(16) char S[36 * APITCH];  // 76032 B
  const int tid = threadIdx.x;
  // grid 2048; XCD-chunked bijective swizzle, chunk 256.
  const int logical = (blockIdx.x & 7) * 256 + (blockIdx.x >> 3);
  const int xh  = logical & 1;
  const int typ = (logical >> 1) & 31;
  const int tzp = logical >> 6;
  const int x0 = xh * 64, y0 = typ * 4, z0 = tzp * 4;

  // ---- staging: interior (x = x0..x0+63): 36 rows x 128 uint4.
  const int th = tid >> 7;        // 0/1
  const int kcol = tid & 127;
  const int wbyte = swz7(32 + kcol * 16);
#pragma unroll 1
  for (int ib = 0; ib < 2; ++ib) {  // two batches of 9 rounds (MLP 9)
    uint4 stg[9];
#pragma unroll
    for (int i = 0; i < 9; ++i) {
      const int r = 2 * (ib * 9 + i) + th;
      const int r6 = r / 6;
      const int zs = min(max(z0 - 1 + r6, 0), 127);
      const int ys = min(max(y0 - 1 + (r - r6 * 6), 0), 127);
      stg[i] = *(const uint4*)(in + (size_t)(zs * 128 + ys) * 1024 +
                               x0 * 8 + kcol * 4);
    }
#pragma unroll
    for (int i = 0; i < 9; ++i) {
      const int r = 2 * (ib * 9 + i) + th;
      *(uint4*)(S + r * APITCH + wbyte) = stg[i];
    }
  }
  // ---- halo columns: slot 0 (x0-1) and slot 65 (x0+64); 144 threads.
  if (tid < 144) {
    const int hr = tid >> 2;        // row 0..35
    const int hp = tid & 3;         // 0,1 -> slot 0 halves; 2,3 -> slot 65
    const int r6 = hr / 6;
    const int zs = min(max(z0 - 1 + r6, 0), 127);
    const int ys = min(max(y0 - 1 + (hr - r6 * 6), 0), 127);
    const int fo = (hp < 2) ? ((x0 - 1) * 8 + hp * 4)
                            : ((x0 + 64) * 8 + (hp - 2) * 4);
    uint4 v = *(const uint4*)(in + (size_t)(zs * 128 + ys) * 1024 + fo);
    const bool zero = xh ? (hp >= 2) : (hp < 2);  // global x=-1 / x=128
    if (zero) v = make_uint4(0u, 0u, 0u, 0u);
    const int sb = (hp < 2) ? (hp * 16) : (65 * 32 + (hp - 2) * 16);
    *(uint4*)(S + hr * APITCH + swz7(sb)) = v;
  }
  __syncthreads();

  // ---- compute: thread = (xp, yp, zo) -> 2x*2y quad ----
  const int xp = tid & 31;
  const int yp = (tid >> 5) & 1;
  const int zo = tid >> 6;
  const int Y = y0 + 2 * yp;
  const int Z = z0 + zo;

  unsigned zokm = 0;
#pragma unroll
  for (int d = 0; d < 3; ++d)
    zokm |= ((unsigned)(Z + d - 1) < 128u) ? (1u << d) : 0u;
  bool yok[2][3];
#pragma unroll
  for (int oy = 0; oy < 2; ++oy)
#pragma unroll
    for (int d = 0; d < 3; ++d)
      yok[oy][d] = (unsigned)(Y + oy + d - 1) < 128u;

  int soff[4][2];
#pragma unroll
  for (int j = 0; j < 4; ++j)
#pragma unroll
    for (int h = 0; h < 2; ++h)
      soff[j][h] = swz7((2 * xp + j) * 32 + h * 16);

  const size_t voxp0 = (size_t)(Z * 128 + Y) * 128 + x0 + 2 * xp;

  f32x4 acc[2][2][2];  // [oy][ox][h], all-static indexing
#pragma unroll
  for (int oy = 0; oy < 2; ++oy)
#pragma unroll
    for (int ox = 0; ox < 2; ++ox)
#pragma unroll
      for (int h = 0; h < 2; ++h)
        acc[oy][ox][h] = (f32x4){0.f, 0.f, 0.f, 0.f};

#pragma unroll 1
  for (int dz = 0; dz < 3; ++dz) {
    const char* Rz = S + ((zo + dz) * 6 + 2 * yp) * APITCH;
    const unsigned short* wz = wn + (size_t)dz * 9 * DHW;
    const bool zv = (zokm >> dz) & 1u;
#pragma unroll
    for (int yr = 0; yr < 4; ++yr) {
      const char* R = Rz + yr * APITCH;
      f32x4 W[4][2];
#pragma unroll
      for (int j = 0; j < 4; ++j)
#pragma unroll
        for (int h = 0; h < 2; ++h)
          W[j][h] = *(const f32x4*)(R + soff[j][h]);
#pragma unroll
      for (int oy = 0; oy < 2; ++oy) {
        const int dy = yr - oy;
        if (dy >= 0 && dy < 3) {
          const bool val = zv && yok[oy][dy];
          const size_t voxp = voxp0 + (size_t)oy * 128;
#pragma unroll
          for (int dxi = 0; dxi < 3; ++dxi) {
            const unsigned u = *(const unsigned*)(
                wz + (size_t)(dy * 3 + dxi) * DHW + voxp);
            const float w0 = val ? b2f((unsigned short)(u & 0xffffu)) : 0.f;
            const float w1 = val ? b2f((unsigned short)(u >> 16)) : 0.f;
#pragma unroll
            for (int h = 0; h < 2; ++h)
#pragma unroll
              for (int c = 0; c < 4; ++c) {
                acc[oy][0][h][c] = fmaf(W[dxi][h][c], w0, acc[oy][0][h][c]);
                acc[oy][1][h][c] =
                    fmaf(W[dxi + 1][h][c], w1, acc[oy][1][h][c]);
              }
          }
        }
      }
    }
  }

  if (FINAL) {
    // planar fp32 [c][vox] -> d_out; float2 = x-pair
#pragma unroll
    for (int oy = 0; oy < 2; ++oy) {
      const size_t voxp = voxp0 + (size_t)oy * 128;
#pragma unroll
      for (int h = 0; h < 2; ++h)
#pragma unroll
        for (int c = 0; c < 4; ++c) {
          float2 o = make_float2(acc[oy][0][h][c], acc[oy][1][h][c]);
          *(float2*)(out + (size_t)(h * 4 + c) * DHW + voxp) = o;
        }
    }
  } else {
    // interleaved fp32 [vox][8]; 64 B contiguous per thread per y
#pragma unroll
    for (int oy = 0; oy < 2; ++oy) {
      const size_t voxp = voxp0 + (size_t)oy * 128;
      f32x4* op = (f32x4*)(out + voxp * 8);
      op[0] = acc[oy][0][0];
      op[1] = acc[oy][0][1];
      op[2] = acc[oy][1][0];
      op[3] = acc[oy][1][1];
    }
  }
}

// ---------------------------------------------------------------------------
extern "C" void kernel_launch(void* const* d_in, const int* in_sizes, int n_in,
                              void* d_out, int out_size, void* d_ws, size_t ws_size,
                              hipStream_t stream) {
  const float* x  = (const float*)d_in[0];
  const float* w1 = (const float*)d_in[1];
  const float* b1 = (const float*)d_in[2];
  const float* w2 = (const float*)d_in[3];
  float* out = (float*)d_out;

  // Workspace (~236 MiB + pads):
  //   [0,   64M): xb(32M)+hb(32M) bf16; reused as ti = ws+256 (64M fp32)
  //   [64M+4K, 172M+4K): wn bf16 planar (27 x DHW)
  //   [172M+12K, 236M+12K): xi fp32 interleaved
  //   then Wpack2, Wpack1. Guard zeros at ti/xi +-32 B (k_prep tail).
  char* ws = (char*)d_ws;
  unsigned short* xb = (unsigned short*)ws;
  unsigned short* hb = (unsigned short*)(ws + (size_t)8 * DHW * 2);
  float* ti = (float*)(ws + 256);  // aliases xb+hb (both dead before adapt)
  unsigned short* wn = (unsigned short*)(ws + (size_t)16 * DHW * 2 + 4096);
  float* xi = (float*)(ws + (size_t)16 * DHW * 2 + 4096 +
                       (size_t)27 * DHW * 2 + 8192);
  unsigned short* Wpack2 =
      (unsigned short*)((char*)xi + (size_t)8 * DHW * 4 + 16384);
  unsigned short* Wpack1 = Wpack2 + 9216;

  dim3 blk(256);
  k_prep<<<55, blk, 0, stream>>>(w1, w2, Wpack2, Wpack1, ti, xi);
  k_xpose<<<DHW / 256, blk, 0, stream>>>(x, xb, xi);
  k_conv1m<<<128 * 64, blk, 0, stream>>>(xb, Wpack1, b1, hb);
  k_conv2<<<128 * 64, blk, 0, stream>>>(hb, Wpack2, wn);
  // adaptive ping-pong on interleaved fp32: xi -> ti -> xi -> out (planar)
  k_adapt8<0><<<2048, blk, 0, stream>>>(xi, wn, ti);
  k_adapt8<0><<<2048, blk, 0, stream>>>(ti, wn, xi);
  k_adapt8<1><<<2048, blk, 0, stream>>>(xi, wn, out);
}

// Round 16
// 351.613 us; speedup vs baseline: 1.1772x; 1.0242x over previous
//
#include <hip/hip_runtime.h>
#include <hip/hip_bf16.h>

// Geometry (fixed): B=1, C=8, D=H=W=128.
constexpr int HW2 = 16384;
constexpr int DHW = 2097152;

// Conv MFMA staging (R16): LDS layout [slot][xi], slot = dz*4+ry (0..11 real,
// 12 zeroed), xi 0..129 (x = -1..128), cell = 16 B. Pitch 130 cells (2080 B).
// Staging writes are lane-linear -> global_load_lds direct; fragment reads
// are 4 rotated 256-B contiguous groups (bases at banks 0/8/16/24).
constexpr int CPITCH = 130;  // cells per slot row

typedef short bf16x8 __attribute__((ext_vector_type(8)));  // 8 bf16 = 4 VGPR
typedef float f32x4  __attribute__((ext_vector_type(4)));

__device__ inline unsigned short f2b(float f) {
  __hip_bfloat16 h = __float2bfloat16(f);
  return *(unsigned short*)&h;
}
__device__ inline float b2f(unsigned short u) {
  __hip_bfloat16 h = *(__hip_bfloat16*)&u;
  return __bfloat162float(h);
}

// Direct global->LDS 16-B copy: lds dest = wave-uniform base + lane*16.
__device__ inline void gld16(const void* g, void* l) {
  __builtin_amdgcn_global_load_lds(
      (const __attribute__((address_space(1))) unsigned int*)g,
      (__attribute__((address_space(3))) unsigned int*)l, 16, 0, 0);
}

// ---------------------------------------------------------------------------
// Prep: pack w1/w2 into MFMA A-fragment order, bf16, dx-split.
// Slot g = s*4+q interpreted as (dz = g>>2 = s, dy = g&3 = q); dy==3 -> 0.
// Tail zero-fills 32-B guards around ti/xi (adapt x-halo reads).
// ---------------------------------------------------------------------------
__global__ __launch_bounds__(256) void k_prep(
    const float* __restrict__ w1, const float* __restrict__ w2,
    unsigned short* __restrict__ Wpack2, unsigned short* __restrict__ Wpack1,
    float* __restrict__ g_ti, float* __restrict__ g_xi) {
  int i = blockIdx.x * 256 + threadIdx.x;
  if (i < 9216) {
    int j = i & 7;
    int lane = (i >> 3) & 63;
    int Mt = (i >> 9) & 1;
    int g2 = i >> 10;         // dx*3 + s
    int s = g2 % 3, dx = g2 / 3;
    int oc = Mt * 16 + (lane & 15);
    int kr = s * 32 + (lane >> 4) * 8 + j;
    int ci = kr & 7, g = kr >> 3;          // g = s*4 + q
    float w = 0.f;
    if (oc < 27 && (g & 3) < 3) {
      int dzr = g >> 2, dyr = g & 3;
      w = w2[(oc * 8 + ci) * 27 + dzr * 9 + dyr * 3 + dx];
    }
    Wpack2[i] = f2b(w);
  }
  int jj = i - 9216;
  if (jj >= 0 && jj < 4608) {
    int j = jj & 7;
    int lane = (jj >> 3) & 63;
    int g2 = jj >> 9;         // dx*3 + s
    int s = g2 % 3, dx = g2 / 3;
    int oc = lane & 15;
    int kr = s * 32 + (lane >> 4) * 8 + j;
    int ci = kr & 7, g = kr >> 3;
    float w = 0.f;
    if (oc < 8 && (g & 3) < 3) {
      int dzr = g >> 2, dyr = g & 3;
      w = w1[(oc * 8 + ci) * 27 + dzr * 9 + dyr * 3 + dx];
    }
    Wpack1[jj] = f2b(w);
  }
  int gg = i - 13824;
  if (gg >= 0 && gg < 32) {
    float* p = (gg < 8)  ? (g_ti - 8 + gg)
             : (gg < 16) ? (g_ti + (size_t)8 * DHW + (gg - 8))
             : (gg < 24) ? (g_xi - 8 + (gg - 16))
                         : (g_xi + (size_t)8 * DHW + (gg - 24));
    *p = 0.f;
  }
}

// ---------------------------------------------------------------------------
// Transpose x: [ci][z][y][x] fp32 -> [z][y][x][ci] bf16 (xb, for conv1 MFMA)
//                                 and [z][y][x][ci] fp32 (xi, for adapt pass)
// ---------------------------------------------------------------------------
__global__ __launch_bounds__(256) void k_xpose(
    const float* __restrict__ x, unsigned short* __restrict__ xb,
    float* __restrict__ xi) {
  int idx = blockIdx.x * 256 + threadIdx.x;  // voxel
  float f[8];
  unsigned v[4];
#pragma unroll
  for (int p = 0; p < 4; ++p) {
    f[2 * p]     = x[(size_t)(2 * p) * DHW + idx];
    f[2 * p + 1] = x[(size_t)(2 * p + 1) * DHW + idx];
    unsigned lo = f2b(f[2 * p]);
    unsigned hi = f2b(f[2 * p + 1]);
    v[p] = lo | (hi << 16);
  }
  ((uint4*)xb)[idx] = make_uint4(v[0], v[1], v[2], v[3]);
  float4* xo = (float4*)(xi + (size_t)idx * 8);
  xo[0] = make_float4(f[0], f[1], f[2], f[3]);
  xo[1] = make_float4(f[4], f[5], f[6], f[7]);
}

// ---------------------------------------------------------------------------
// Conv staging (R16): global_load_lds direct. 12 rows x 2 halves = 24
// wave-tasks, 6 per wave; row validity is wave-uniform (invalid -> zeros).
// Zero tasks: slot 12 (130 cells) + x-halo cells (xi 0,129) of rows 0..11.
// ---------------------------------------------------------------------------
#define STAGE_G(srcp)                                                      \
  {                                                                        \
    uint4* dstc = (uint4*)T;                                               \
    if (tid < 130) dstc[12 * CPITCH + tid] = make_uint4(0u, 0u, 0u, 0u);   \
    if (tid < 24) {                                                        \
      const int row = tid >> 1, xih = (tid & 1) ? 129 : 0;                 \
      dstc[row * CPITCH + xih] = make_uint4(0u, 0u, 0u, 0u);               \
    }                                                                      \
    const int wv_ = tid >> 6;                                              \
    const int l_  = tid & 63;                                              \
    _Pragma("unroll")                                                      \
    for (int i = 0; i < 6; ++i) {                                          \
      const int t = wv_ + 4 * i;                                           \
      const int row = t >> 1, hf = t & 1;                                  \
      const int dz = row >> 2, ry = row & 3;                               \
      const int z = z0 + dz - 1, y = y0 + ry - 1;                          \
      char* lb = (char*)T + (size_t)(row * CPITCH + 1 + hf * 64) * 16;     \
      if (((unsigned)z < 128u) & ((unsigned)y < 128u)) {                   \
        const uint4* g = (srcp) + (size_t)(z * 128 + y) * 128 +            \
                         hf * 64 + l_;                                     \
        gld16((const void*)g, (void*)lb);                                  \
      } else {                                                             \
        *(uint4*)(lb + l_ * 16) = make_uint4(0u, 0u, 0u, 0u);              \
      }                                                                    \
    }                                                                      \
  }

// ---------------------------------------------------------------------------
// Kernel 1: conv3d(x, w1) + bias + ReLU (8 -> 8), implicit-GEMM MFMA.
// y-pair per block; grid 128 z * 64 ypairs = 8192.
// ---------------------------------------------------------------------------
__global__ __launch_bounds__(256, 3) void k_conv1m(
    const unsigned short* __restrict__ xb,
    const unsigned short* __restrict__ Wpack1,
    const float* __restrict__ b1, unsigned short* __restrict__ hb) {
  __shared__ __align__(16) unsigned short T[13 * CPITCH * 8];
  const int tid  = threadIdx.x;
  const int lane = tid & 63;
  const int wv   = tid >> 6;
  const int logical = (blockIdx.x & 7) * 1024 + (blockIdx.x >> 3);
  const int z0 = logical >> 6;
  const int y0 = (logical & 63) * 2;

  bf16x8 wf[3][3];
  {
    const bf16x8* wp = (const bf16x8*)Wpack1;
#pragma unroll
    for (int dx = 0; dx < 3; ++dx)
#pragma unroll
      for (int s = 0; s < 3; ++s)
        wf[dx][s] = wp[(dx * 3 + s) * 64 + lane];
  }

  const uint4* src = (const uint4*)xb;
  STAGE_G(src);
  __syncthreads();

  f32x4 acc[2][2];  // [r][nt]
#pragma unroll
  for (int r = 0; r < 2; ++r)
#pragma unroll
    for (int nt = 0; nt < 2; ++nt) acc[r][nt] = (f32x4){0.f, 0.f, 0.f, 0.f};

  const int n = lane & 15;
  const int q = lane >> 4;
  const int xbase = wv * 32 + n;

#pragma unroll
  for (int dx = 0; dx < 3; ++dx) {
#pragma unroll
    for (int s = 0; s < 3; ++s) {
      bf16x8 bfr[2][2];
#pragma unroll
      for (int r = 0; r < 2; ++r)
#pragma unroll
        for (int nt = 0; nt < 2; ++nt) {
          int off = ((s * 4 + q + r) * CPITCH + xbase + nt * 16 + dx) * 8;
          bfr[r][nt] = *(const bf16x8*)&T[off];
        }
#pragma unroll
      for (int r = 0; r < 2; ++r)
#pragma unroll
        for (int nt = 0; nt < 2; ++nt)
          acc[r][nt] = __builtin_amdgcn_mfma_f32_16x16x32_bf16(
              wf[dx][s], bfr[r][nt], acc[r][nt], 0, 0, 0);
    }
  }

  if (q < 2) {
#pragma unroll
    for (int r = 0; r < 2; ++r) {
      const int voxrow = (z0 * 128 + y0 + r) * 128;
#pragma unroll
      for (int nt = 0; nt < 2; ++nt) {
        const int vox = voxrow + wv * 32 + nt * 16 + n;
        ushort4 o;
        o.x = f2b(fmaxf(acc[r][nt][0] + b1[q * 4 + 0], 0.f));
        o.y = f2b(fmaxf(acc[r][nt][1] + b1[q * 4 + 1], 0.f));
        o.z = f2b(fmaxf(acc[r][nt][2] + b1[q * 4 + 2], 0.f));
        o.w = f2b(fmaxf(acc[r][nt][3] + b1[q * 4 + 3], 0.f));
        *(ushort4*)(hb + (size_t)vox * 8 + q * 4) = o;
      }
    }
  }
}

// ---------------------------------------------------------------------------
// Kernel 2: conv3d(h, w2) (8 -> 27) + fused L1 norm, implicit-GEMM MFMA.
// y-pair per block; grid 8192.
// ---------------------------------------------------------------------------
__global__ __launch_bounds__(256, 2) void k_conv2(
    const unsigned short* __restrict__ hb,
    const unsigned short* __restrict__ Wpack2,
    unsigned short* __restrict__ wn) {
  __shared__ __align__(16) unsigned short T[13 * CPITCH * 8];
  const int tid  = threadIdx.x;
  const int lane = tid & 63;
  const int wv   = tid >> 6;
  const int logical = (blockIdx.x & 7) * 1024 + (blockIdx.x >> 3);
  const int z0 = logical >> 6;
  const int y0 = (logical & 63) * 2;

  bf16x8 wf[3][3][2];
  {
    const bf16x8* wp = (const bf16x8*)Wpack2;
#pragma unroll
    for (int dx = 0; dx < 3; ++dx)
#pragma unroll
      for (int s = 0; s < 3; ++s)
#pragma unroll
        for (int mt = 0; mt < 2; ++mt)
          wf[dx][s][mt] = wp[((dx * 3 + s) * 2 + mt) * 64 + lane];
  }

  const uint4* src = (const uint4*)hb;
  STAGE_G(src);
  __syncthreads();

  f32x4 acc[2][2][2];  // [r][nt][mt]
#pragma unroll
  for (int r = 0; r < 2; ++r)
#pragma unroll
    for (int nt = 0; nt < 2; ++nt)
#pragma unroll
      for (int mt = 0; mt < 2; ++mt)
        acc[r][nt][mt] = (f32x4){0.f, 0.f, 0.f, 0.f};

  const int n = lane & 15;
  const int q = lane >> 4;
  const int xbase = wv * 32 + n;

#pragma unroll
  for (int dx = 0; dx < 3; ++dx) {
#pragma unroll
    for (int s = 0; s < 3; ++s) {
      bf16x8 bfr[2][2];
#pragma unroll
      for (int r = 0; r < 2; ++r)
#pragma unroll
        for (int nt = 0; nt < 2; ++nt) {
          int off = ((s * 4 + q + r) * CPITCH + xbase + nt * 16 + dx) * 8;
          bfr[r][nt] = *(const bf16x8*)&T[off];
        }
#pragma unroll
      for (int r = 0; r < 2; ++r)
#pragma unroll
        for (int mt = 0; mt < 2; ++mt)
#pragma unroll
          for (int nt = 0; nt < 2; ++nt)
            acc[r][nt][mt] = __builtin_amdgcn_mfma_f32_16x16x32_bf16(
                wf[dx][s][mt], bfr[r][nt], acc[r][nt][mt], 0, 0, 0);
    }
  }

#pragma unroll
  for (int r = 0; r < 2; ++r) {
    const int voxrow = (z0 * 128 + y0 + r) * 128;
#pragma unroll
    for (int nt = 0; nt < 2; ++nt) {
      float ns = 0.f;
#pragma unroll
      for (int rr = 0; rr < 4; ++rr) ns += fabsf(acc[r][nt][0][rr]);
#pragma unroll
      for (int rr = 0; rr < 4; ++rr) {
        int oc = 16 + q * 4 + rr;
        ns += (oc < 27) ? fabsf(acc[r][nt][1][rr]) : 0.f;
      }
      ns += __shfl_xor(ns, 16);
      ns += __shfl_xor(ns, 32);
      float sc = 1.f / fmaxf(ns, 1e-12f);
      const int vox = voxrow + wv * 32 + nt * 16 + n;
#pragma unroll
      for (int rr = 0; rr < 4; ++rr) {
        int oc = q * 4 + rr;
        wn[(size_t)oc * DHW + vox] = f2b(acc[r][nt][0][rr] * sc);
      }
#pragma unroll
      for (int rr = 0; rr < 4; ++rr) {
        int oc = 16 + q * 4 + rr;
        if (oc < 27)
          wn[(size_t)oc * DHW + vox] = f2b(acc[r][nt][1][rr] * sc);
      }
    }
  }
}

// ---------------------------------------------------------------------------
// Kernel 3 (R16 = R12 + gload_lds staging): quad-tiled adaptive conv.
// LDS layout + swizzle + compute bit-identical to R12 (57-60 us proven).
// Staging: global_load_lds with INVERSE-SWIZZLED per-lane source (rule #21:
// linear LDS dest + pre-swizzled global src; swz7 is an involution, so
// physical byte q holds logical swz7(q)). 36 rows x 2 halves = 72 wave-
// tasks, 18/wave. Frees the stg[] registers; no VGPR round trip.
// ---------------------------------------------------------------------------
constexpr int APITCH = 2112;  // 66 slots * 32 B
__device__ inline int swz7(int off) { return off ^ (((off >> 7) & 7) << 4); }

template <int FINAL>
__global__ __launch_bounds__(256, 1) void k_adapt10(
    const float* __restrict__ in, const unsigned short* __restrict__ wn,
    float* __restrict__ out) {
  __shared__ __align__(16) char S[36 * APITCH];  // 76032 B
  const int tid = threadIdx.x;
  // grid 2048; XCD-chunked bijective swizzle, chunk 256.
  const int logical = (blockIdx.x & 7) * 256 + (blockIdx.x >> 3);
  const int xh  = logical & 1;
  const int typ = (logical >> 1) & 31;
  const int tzp = logical >> 6;
  const int x0 = xh * 64, y0 = typ * 4, z0 = tzp * 4;

  // ---- staging: interior via global_load_lds (inverse-swizzled source) ----
  {
    const int wv_ = tid >> 6;
    const int l_  = tid & 63;
#pragma unroll
    for (int i = 0; i < 18; ++i) {
      const int t = wv_ + 4 * i;          // 0..71
      const int r = t >> 1, hf = t & 1;
      const int r6 = r / 6;
      const int zs = min(max(z0 - 1 + r6, 0), 127);
      const int ys = min(max(y0 - 1 + (r - r6 * 6), 0), 127);
      const int q = 32 + hf * 1024 + l_ * 16;   // physical within-row byte
      const int p = swz7(q);                    // logical byte it must hold
      const char* g = (const char*)in + (size_t)(zs * 128 + ys) * 4096 +
                      (size_t)x0 * 32 + (p - 32);
      char* lb = S + r * APITCH + 32 + hf * 1024;  // wave-uniform base
      gld16((const void*)g, (void*)lb);
    }
  }
  // ---- halo columns: slot 0 (x0-1) and slot 65 (x0+64); 144 threads.
  if (tid < 144) {
    const int hr = tid >> 2;        // row 0..35
    const int hp = tid & 3;         // 0,1 -> slot 0 halves; 2,3 -> slot 65
    const int r6 = hr / 6;
    const int zs = min(max(z0 - 1 + r6, 0), 127);
    const int ys = min(max(y0 - 1 + (hr - r6 * 6), 0), 127);
    const int fo = (hp < 2) ? ((x0 - 1) * 8 + hp * 4)
                            : ((x0 + 64) * 8 + (hp - 2) * 4);
    uint4 v = *(const uint4*)(in + (size_t)(zs * 128 + ys) * 1024 + fo);
    const bool zero = xh ? (hp >= 2) : (hp < 2);  // global x=-1 / x=128
    if (zero) v = make_uint4(0u, 0u, 0u, 0u);
    const int sb = (hp < 2) ? (hp * 16) : (65 * 32 + (hp - 2) * 16);
    *(uint4*)(S + hr * APITCH + swz7(sb)) = v;
  }
  __syncthreads();

  // ---- compute: thread = (xp, yp, zo) -> 2x*2y quad ----
  const int xp = tid & 31;
  const int yp = (tid >> 5) & 1;
  const int zo = tid >> 6;
  const int Y = y0 + 2 * yp;
  const int Z = z0 + zo;

  unsigned zokm = 0;
#pragma unroll
  for (int d = 0; d < 3; ++d)
    zokm |= ((unsigned)(Z + d - 1) < 128u) ? (1u << d) : 0u;
  bool yok[2][3];
#pragma unroll
  for (int oy = 0; oy < 2; ++oy)
#pragma unroll
    for (int d = 0; d < 3; ++d)
      yok[oy][d] = (unsigned)(Y + oy + d - 1) < 128u;

  int soff[4][2];
#pragma unroll
  for (int j = 0; j < 4; ++j)
#pragma unroll
    for (int h = 0; h < 2; ++h)
      soff[j][h] = swz7((2 * xp + j) * 32 + h * 16);

  const size_t voxp0 = (size_t)(Z * 128 + Y) * 128 + x0 + 2 * xp;

  f32x4 acc[2][2][2];  // [oy][ox][h], all-static indexing
#pragma unroll
  for (int oy = 0; oy < 2; ++oy)
#pragma unroll
    for (int ox = 0; ox < 2; ++ox)
#pragma unroll
      for (int h = 0; h < 2; ++h)
        acc[oy][ox][h] = (f32x4){0.f, 0.f, 0.f, 0.f};

#pragma unroll 1
  for (int dz = 0; dz < 3; ++dz) {
    const char* Rz = S + ((zo + dz) * 6 + 2 * yp) * APITCH;
    const unsigned short* wz = wn + (size_t)dz * 9 * DHW;
    const bool zv = (zokm >> dz) & 1u;
#pragma unroll
    for (int yr = 0; yr < 4; ++yr) {
      const char* R = Rz + yr * APITCH;
      f32x4 W[4][2];
#pragma unroll
      for (int j = 0; j < 4; ++j)
#pragma unroll
        for (int h = 0; h < 2; ++h)
          W[j][h] = *(const f32x4*)(R + soff[j][h]);
#pragma unroll
      for (int oy = 0; oy < 2; ++oy) {
        const int dy = yr - oy;
        if (dy >= 0 && dy < 3) {
          const bool val = zv && yok[oy][dy];
          const size_t voxp = voxp0 + (size_t)oy * 128;
#pragma unroll
          for (int dxi = 0; dxi < 3; ++dxi) {
            const unsigned u = *(const unsigned*)(
                wz + (size_t)(dy * 3 + dxi) * DHW + voxp);
            const float w0 = val ? b2f((unsigned short)(u & 0xffffu)) : 0.f;
            const float w1 = val ? b2f((unsigned short)(u >> 16)) : 0.f;
#pragma unroll
            for (int h = 0; h < 2; ++h)
#pragma unroll
              for (int c = 0; c < 4; ++c) {
                acc[oy][0][h][c] = fmaf(W[dxi][h][c], w0, acc[oy][0][h][c]);
                acc[oy][1][h][c] =
                    fmaf(W[dxi + 1][h][c], w1, acc[oy][1][h][c]);
              }
          }
        }
      }
    }
  }

  if (FINAL) {
    // planar fp32 [c][vox] -> d_out; float2 = x-pair
#pragma unroll
    for (int oy = 0; oy < 2; ++oy) {
      const size_t voxp = voxp0 + (size_t)oy * 128;
#pragma unroll
      for (int h = 0; h < 2; ++h)
#pragma unroll
        for (int c = 0; c < 4; ++c) {
          float2 o = make_float2(acc[oy][0][h][c], acc[oy][1][h][c]);
          *(float2*)(out + (size_t)(h * 4 + c) * DHW + voxp) = o;
        }
    }
  } else {
    // interleaved fp32 [vox][8]; 64 B contiguous per thread per y
#pragma unroll
    for (int oy = 0; oy < 2; ++oy) {
      const size_t voxp = voxp0 + (size_t)oy * 128;
      f32x4* op = (f32x4*)(out + voxp * 8);
      op[0] = acc[oy][0][0];
      op[1] = acc[oy][0][1];
      op[2] = acc[oy][1][0];
      op[3] = acc[oy][1][1];
    }
  }
}

// ---------------------------------------------------------------------------
extern "C" void kernel_launch(void* const* d_in, const int* in_sizes, int n_in,
                              void* d_out, int out_size, void* d_ws, size_t ws_size,
                              hipStream_t stream) {
  const float* x  = (const float*)d_in[0];
  const float* w1 = (const float*)d_in[1];
  const float* b1 = (const float*)d_in[2];
  const float* w2 = (const float*)d_in[3];
  float* out = (float*)d_out;

  // Workspace (~236 MiB + pads):
  //   [0,   64M): xb(32M)+hb(32M) bf16; reused as ti = ws+256 (64M fp32)
  //   [64M+4K, 172M+4K): wn bf16 planar (27 x DHW)
  //   [172M+12K, 236M+12K): xi fp32 interleaved
  //   then Wpack2, Wpack1. Guard zeros at ti/xi +-32 B (k_prep tail).
  char* ws = (char*)d_ws;
  unsigned short* xb = (unsigned short*)ws;
  unsigned short* hb = (unsigned short*)(ws + (size_t)8 * DHW * 2);
  float* ti = (float*)(ws + 256);  // aliases xb+hb (both dead before adapt)
  unsigned short* wn = (unsigned short*)(ws + (size_t)16 * DHW * 2 + 4096);
  float* xi = (float*)(ws + (size_t)16 * DHW * 2 + 4096 +
                       (size_t)27 * DHW * 2 + 8192);
  unsigned short* Wpack2 =
      (unsigned short*)((char*)xi + (size_t)8 * DHW * 4 + 16384);
  unsigned short* Wpack1 = Wpack2 + 9216;

  dim3 blk(256);
  k_prep<<<55, blk, 0, stream>>>(w1, w2, Wpack2, Wpack1, ti, xi);
  k_xpose<<<DHW / 256, blk, 0, stream>>>(x, xb, xi);
  k_conv1m<<<128 * 64, blk, 0, stream>>>(xb, Wpack1, b1, hb);
  k_conv2<<<128 * 64, blk, 0, stream>>>(hb, Wpack2, wn);
  // adaptive ping-pong on interleaved fp32: xi -> ti -> xi -> out (planar)
  k_adapt10<0><<<2048, blk, 0, stream>>>(xi, wn, ti);
  k_adapt10<0><<<2048, blk, 0, stream>>>(ti, wn, xi);
  k_adapt10<1><<<2048, blk, 0, stream>>>(xi, wn, out);
}